// Round 5
// baseline (4010.676 us; speedup 1.0000x reference)
//
#include <hip/hip_runtime.h>
#include <hip/hip_bf16.h>
#include <cstddef>

// ---------------------------------------------------------------------------
// EncoderModule: 5x causal conv1d (K=7) + ELU, then 2x VQ argmin (1024 codes, D=64)
// B=64, L=48000, strides 2,2,2,3,1; channels 1->16->32->64->64->128
// Output: int32 indices, shape (2, 64, 2000)
//
// VQ strategy: bf16 MFMA computes approximate scores s~ = ||c||^2 - 2*dot(z~,c~)
// (||c||^2 exact fp32). Track per-t best+second; if gap < MARGIN (>>10 sigma of
// bf16 rounding error), flag t and rescore exactly in fp32 (identical formula
// to the previously-passing fp32 kernels). Unflagged results are provably the
// true argmin; flagged ones are recomputed exactly.
// ---------------------------------------------------------------------------

using bf16x8 = __attribute__((ext_vector_type(8))) short;
using f32x4  = __attribute__((ext_vector_type(4))) float;

static __device__ __forceinline__ short f2bf(float f) {
    __hip_bfloat16 h = __float2bfloat16(f);   // RNE
    union { __hip_bfloat16 h; short s; } u; u.h = h;
    return u.s;
}

// ---------------- conv (unchanged from round 4) ----------------
template<int CIN, int S, int CO_T, int TT>
__global__ __launch_bounds__(256) void conv_wave_kernel(
    const float* __restrict__ x, const float* __restrict__ w,
    const float* __restrict__ bias, float* __restrict__ y,
    int B, int Lin, int Lout, int Cout)
{
    constexpr int NT   = 64 * TT;
    constexpr int XLEN = (NT - 1) * S + 7;
    __shared__ float xs[CIN][XLEN];

    int tb  = blockIdx.x;
    int cbk = blockIdx.y;
    int b   = blockIdx.z;
    int t0  = tb * NT;
    int tid  = threadIdx.x;
    int lane = tid & 63;
    int wv   = __builtin_amdgcn_readfirstlane(tid >> 6);

    const float* xb = x + (size_t)b * CIN * Lin;
    int g0 = t0 * S - 6;
    for (int i = tid; i < CIN * XLEN; i += 256) {
        int ci = i / XLEN, xo = i % XLEN;
        int gx = g0 + xo;
        xs[ci][xo] = (gx >= 0 && gx < Lin) ? xb[(size_t)ci * Lin + gx] : 0.0f;
    }
    __syncthreads();

    int co0 = cbk * (4 * CO_T) + wv * CO_T;
    const float* wbase = w + (size_t)co0 * CIN * 7;

    float acc[CO_T][TT];
    #pragma unroll
    for (int c = 0; c < CO_T; ++c)
        #pragma unroll
        for (int u = 0; u < TT; ++u) acc[c][u] = 0.0f;

    for (int ci = 0; ci < CIN; ++ci) {
        float xw[TT][7];
        #pragma unroll
        for (int u = 0; u < TT; ++u)
            #pragma unroll
            for (int k = 0; k < 7; ++k)
                xw[u][k] = xs[ci][(lane + 64 * u) * S + k];
        #pragma unroll
        for (int c = 0; c < CO_T; ++c) {
            const float* wp = wbase + (size_t)c * CIN * 7 + ci * 7;
            #pragma unroll
            for (int k = 0; k < 7; ++k) {
                float wk = wp[k];
                #pragma unroll
                for (int u = 0; u < TT; ++u)
                    acc[c][u] = fmaf(wk, xw[u][k], acc[c][u]);
            }
        }
    }

    #pragma unroll
    for (int u = 0; u < TT; ++u) {
        int t = t0 + lane + 64 * u;
        if (t < Lout) {
            #pragma unroll
            for (int c = 0; c < CO_T; ++c) {
                float v = acc[c][u] + bias[co0 + c];
                y[((size_t)b * Cout + co0 + c) * Lout + t] = v > 0.0f ? v : expm1f(v);
            }
        }
    }
}

// ---------------- VQ prep: cc (fp32) + codebook bf16 in B-fragment layout ----
// frag layout: [cb][nt(64)][kc(2)][lane(64)][j(8)] bf16, where for
// mfma_16x16x32: B element (k = kc*32 + (lane>>4)*8 + j, n = nt*16 + (lane&15))
__global__ __launch_bounds__(256) void vq_prep_kernel(
    const float* __restrict__ cbs, float* __restrict__ cc, short* __restrict__ cbf)
{
    int c = blockIdx.x * 256 + threadIdx.x;   // 0..2047
    if (c >= 2048) return;
    int cb = c >> 10, nl = c & 1023;
    const float* row = cbs + (size_t)c * 64;
    float v[64];
    float s = 0.f;
    #pragma unroll
    for (int i = 0; i < 16; ++i) {
        float4 q = ((const float4*)row)[i];
        v[4*i+0] = q.x; v[4*i+1] = q.y; v[4*i+2] = q.z; v[4*i+3] = q.w;
        s += q.x*q.x + q.y*q.y + q.z*q.z + q.w*q.w;
    }
    cc[c] = s;
    int nt = nl >> 4, nc = nl & 15;
    #pragma unroll
    for (int kc = 0; kc < 2; ++kc)
        #pragma unroll
        for (int lh = 0; lh < 4; ++lh) {
            bf16x8 pk;
            #pragma unroll
            for (int j = 0; j < 8; ++j) pk[j] = f2bf(v[kc*32 + lh*8 + j]);
            size_t off = ((((size_t)cb*64 + nt)*2 + kc)*64 + (lh*16 + nc)) * 8;
            *(bf16x8*)(cbf + off) = pk;
        }
}

__global__ void zero_cnt_kernel(int* cnt) {
    if (threadIdx.x == 0 && blockIdx.x == 0) *cnt = 0;
}

// ---------------- VQ main: bf16 MFMA scores + best/second + flag ------------
#define VQ_MARGIN 1.0f

__global__ __launch_bounds__(256) void vq_mfma_kernel(
    const float* __restrict__ z, const short* __restrict__ cbf,
    const float* __restrict__ ccg, int* __restrict__ out,
    int* __restrict__ cnt, int* __restrict__ list)
{
    __shared__ short zf[8*2*64*8];      // 16 KB: A-frags, [mt(8)][kc(2)][lane][j]
    __shared__ short cbc[16*2*64*8];    // 32 KB: B-frag chunk (256 codes)
    __shared__ float ccl[256];

    const int T = 2000;
    int mblk = blockIdx.x;   // 16 m-blocks of 128 t
    int cb   = blockIdx.y;
    int b    = blockIdx.z;
    int t0   = mblk * 128;
    int tid  = threadIdx.x;
    int lane = tid & 63;
    int wv   = tid >> 6;

    // ---- stage z tile (128 t x 64 d) into bf16 A-fragments ----
    const float* zb = z + ((size_t)b*128 + (size_t)cb*64) * T;
    bool tail = (t0 + 128 > T);
    #pragma unroll
    for (int p = 0; p < 8; ++p) {
        int d    = p*8 + (tid >> 5);
        int toff = (tid & 31) * 4;
        float qa[4];
        if (!tail) {
            float4 q = *(const float4*)(zb + (size_t)d*T + t0 + toff);
            qa[0]=q.x; qa[1]=q.y; qa[2]=q.z; qa[3]=q.w;
        } else {
            #pragma unroll
            for (int u = 0; u < 4; ++u) {
                int tt = t0 + toff + u; if (tt > T-1) tt = T-1;
                qa[u] = zb[(size_t)d*T + tt];
            }
        }
        #pragma unroll
        for (int u = 0; u < 4; ++u) {
            int tl = toff + u;
            int mt = tl >> 4;
            int lw = ((d & 31) >> 3) * 16 + (tl & 15);
            int kc = d >> 5;
            zf[(((mt*2 + kc)*64) + lw)*8 + (d & 7)] = f2bf(qa[u]);
        }
    }
    __syncthreads();

    // A-fragments for this wave (rows t0 + (wv*2+mtl)*16 + ...)
    bf16x8 a[2][2];
    #pragma unroll
    for (int mtl = 0; mtl < 2; ++mtl)
        #pragma unroll
        for (int kc = 0; kc < 2; ++kc)
            a[mtl][kc] = *(const bf16x8*)&zf[((((wv*2+mtl)*2 + kc)*64) + lane)*8];

    float best[2][4], second[2][4]; int bidx[2][4];
    #pragma unroll
    for (int m = 0; m < 2; ++m)
        #pragma unroll
        for (int j = 0; j < 4; ++j) { best[m][j] = 3.4e38f; second[m][j] = 3.4e38f; bidx[m][j] = 0; }

    const short* cbase = cbf + (size_t)cb * (64*2*64*8);
    const float* ccb   = ccg + cb * 1024;

    for (int ch = 0; ch < 4; ++ch) {
        __syncthreads();   // previous chunk consumed
        {
            const float4* src = (const float4*)(cbase + (size_t)ch * (16*2*64*8));
            float4* dst = (float4*)cbc;
            #pragma unroll
            for (int i = 0; i < 8; ++i) dst[tid + 256*i] = src[tid + 256*i];
            ccl[tid] = ccb[ch*256 + tid];
        }
        __syncthreads();

        for (int ntl = 0; ntl < 16; ++ntl) {
            bf16x8 b0 = *(const bf16x8*)&cbc[((ntl*2 + 0)*64 + lane)*8];
            bf16x8 b1 = *(const bf16x8*)&cbc[((ntl*2 + 1)*64 + lane)*8];
            float ccv = ccl[ntl*16 + (lane & 15)];
            int  code = ch*256 + ntl*16 + (lane & 15);
            #pragma unroll
            for (int mtl = 0; mtl < 2; ++mtl) {
                f32x4 acc = {0.f, 0.f, 0.f, 0.f};
                acc = __builtin_amdgcn_mfma_f32_16x16x32_bf16(a[mtl][0], b0, acc, 0, 0, 0);
                acc = __builtin_amdgcn_mfma_f32_16x16x32_bf16(a[mtl][1], b1, acc, 0, 0, 0);
                #pragma unroll
                for (int j = 0; j < 4; ++j) {
                    float s = fmaf(-2.0f, acc[j], ccv);
                    bool lt = s < best[mtl][j];
                    second[mtl][j] = fminf(second[mtl][j], fmaxf(best[mtl][j], s));
                    best[mtl][j]   = fminf(best[mtl][j], s);
                    bidx[mtl][j]   = lt ? code : bidx[mtl][j];
                }
            }
        }
    }

    // merge across the 16 col-lanes (same rows, different code slices)
    #pragma unroll
    for (int m = 0; m < 2; ++m)
        #pragma unroll
        for (int j = 0; j < 4; ++j) {
            float bv = best[m][j], sv = second[m][j]; int bi = bidx[m][j];
            #pragma unroll
            for (int d = 1; d < 16; d <<= 1) {
                float ob = __shfl_xor(bv, d, 64);
                float os = __shfl_xor(sv, d, 64);
                int   oi = __shfl_xor(bi, d, 64);
                float loser = fmaxf(bv, ob);
                sv = fminf(fminf(sv, os), loser);
                bool sw = ob < bv;
                bv = fminf(bv, ob);
                bi = sw ? oi : bi;
            }
            if ((lane & 15) == 0) {
                int t = t0 + (wv*2 + m)*16 + (lane >> 4)*4 + j;
                if (t < T) {
                    out[((size_t)cb*64 + b)*T + t] = bi;
                    if (sv - bv < VQ_MARGIN) {
                        int pos = atomicAdd(cnt, 1);
                        list[pos] = (cb << 17) | (b << 11) | t;
                    }
                }
            }
        }
}

// ---------------- VQ rescore: exact fp32 for flagged t ----------------------
__global__ __launch_bounds__(256) void vq_rescore_kernel(
    const float* __restrict__ z, const float* __restrict__ cbs,
    const float* __restrict__ ccg, const int* __restrict__ cnt,
    const int* __restrict__ list, int* __restrict__ out)
{
    const int T = 2000;
    int lane = threadIdx.x & 63;
    int gw = (blockIdx.x * 256 + threadIdx.x) >> 6;   // global wave id
    int count = *cnt;

    for (int i = gw; i < count; i += 1024) {
        int e = list[i];
        int cb = e >> 17, b = (e >> 11) & 63, t = e & 2047;
        const float* zb = z + ((size_t)b*128 + (size_t)cb*64) * T + t;
        float zr[64];
        #pragma unroll
        for (int d = 0; d < 64; ++d) zr[d] = zb[(size_t)d * T];

        const float* cbase = cbs + (size_t)cb * 1024 * 64;
        const float* ccb   = ccg + cb * 1024;
        float bv = 3.4e38f; int bi = 0x7fffffff;
        for (int ii = 0; ii < 16; ++ii) {
            int code = ii*64 + lane;
            const float4* cp = (const float4*)(cbase + (size_t)code * 64);
            float d0 = 0.f, d1 = 0.f, d2 = 0.f, d3 = 0.f;
            #pragma unroll
            for (int q = 0; q < 16; ++q) {
                float4 cv = cp[q];
                d0 = fmaf(zr[4*q+0], cv.x, d0);
                d1 = fmaf(zr[4*q+1], cv.y, d1);
                d2 = fmaf(zr[4*q+2], cv.z, d2);
                d3 = fmaf(zr[4*q+3], cv.w, d3);
            }
            float s = fmaf(-2.0f, (d0 + d1) + (d2 + d3), ccb[code]);
            if (s < bv) { bv = s; bi = code; }
        }
        #pragma unroll
        for (int d = 1; d < 64; d <<= 1) {
            float ov = __shfl_xor(bv, d, 64);
            int   oi = __shfl_xor(bi, d, 64);
            if (ov < bv || (ov == bv && oi < bi)) { bv = ov; bi = oi; }
        }
        if (lane == 0) out[((size_t)cb*64 + b)*T + t] = bi;
    }
}

extern "C" void kernel_launch(void* const* d_in, const int* in_sizes, int n_in,
                              void* d_out, int out_size, void* d_ws, size_t ws_size,
                              hipStream_t stream)
{
    const float* x   = (const float*)d_in[0];
    const float* w0  = (const float*)d_in[1];
    const float* b0  = (const float*)d_in[2];
    const float* w1  = (const float*)d_in[3];
    const float* b1  = (const float*)d_in[4];
    const float* w2  = (const float*)d_in[5];
    const float* b2  = (const float*)d_in[6];
    const float* w3  = (const float*)d_in[7];
    const float* b3  = (const float*)d_in[8];
    const float* wq  = (const float*)d_in[9];
    const float* bq  = (const float*)d_in[10];
    const float* cbs = (const float*)d_in[11];
    int* out = (int*)d_out;

    constexpr int B = 64;
    constexpr size_t BUF = 24576000;
    float* bufA = (float*)d_ws;
    float* bufB = bufA + BUF;
    // prep area: inside bufB, beyond conv3's 8.192M floats (placed at +16M).
    // Written after conv2 (conv1's full-bufB data already consumed), never
    // touched by conv3 (writes [0,8.192M)) or conv4 (reads [0,8.192M)).
    float* prep = bufB + 16000000;
    short* cbf  = (short*)prep;                 // 262144 bf16
    float* cc   = prep + 131072;                // 2048 f32
    int*   cnt  = (int*)(cc + 2048);            // 1 int (+pad)
    int*   list = cnt + 4;                      // up to 256000 ints

    // conv0: (B,1,48000) -> (B,16,24000)
    conv_wave_kernel<1, 2, 4, 2><<<dim3(188, 1, B), 256, 0, stream>>>(
        x, w0, b0, bufA, B, 48000, 24000, 16);
    // conv1: (B,16,24000) -> (B,32,12000)
    conv_wave_kernel<16, 2, 8, 2><<<dim3(94, 1, B), 256, 0, stream>>>(
        bufA, w1, b1, bufB, B, 24000, 12000, 32);
    // conv2: (B,32,12000) -> (B,64,6000)
    conv_wave_kernel<32, 2, 8, 2><<<dim3(47, 2, B), 256, 0, stream>>>(
        bufB, w2, b2, bufA, B, 12000, 6000, 64);

    // prep (after conv2: bufB prep region is free from here on)
    vq_prep_kernel<<<8, 256, 0, stream>>>(cbs, cc, cbf);
    zero_cnt_kernel<<<1, 64, 0, stream>>>(cnt);

    // conv3: (B,64,6000) -> (B,64,2000)
    conv_wave_kernel<64, 3, 8, 1><<<dim3(32, 2, B), 256, 0, stream>>>(
        bufA, w3, b3, bufB, B, 6000, 2000, 64);
    // conv4: (B,64,2000) -> (B,128,2000)
    conv_wave_kernel<64, 1, 8, 2><<<dim3(16, 4, B), 256, 0, stream>>>(
        bufB, wq, bq, bufA, B, 2000, 2000, 128);

    // VQ: bf16 MFMA + flag, then exact fp32 rescore of flagged t
    vq_mfma_kernel<<<dim3(16, 2, B), 256, 0, stream>>>(bufA, cbf, cc, out, cnt, list);
    vq_rescore_kernel<<<256, 256, 0, stream>>>(bufA, cbs, cc, cnt, list, out);
}

// Round 6
// 957.253 us; speedup vs baseline: 4.1898x; 4.1898x over previous
//
#include <hip/hip_runtime.h>
#include <hip/hip_bf16.h>
#include <cstddef>

// ---------------------------------------------------------------------------
// EncoderModule: 5x causal conv1d (K=7) + ELU, then 2x VQ argmin (1024 codes, D=64)
// B=64, L=48000, strides 2,2,2,3,1; channels 1->16->32->64->64->128
// Output: int32 indices, shape (2, 64, 2000)
//
// VQ: split-bf16 MFMA scores. z=zh+zl, c=ch+cl (bf16 hi + bf16 residual);
// dot ~= zh.ch + zh.cl + zl.ch via 3 MFMA passes -> |score error| <~ 2e-3.
// Track best+second; gap < 0.02 -> exact fp32 rescore. Unflagged t provably
// match the fp32 argmin.
// ---------------------------------------------------------------------------

using bf16x8 = __attribute__((ext_vector_type(8))) short;
using f32x4  = __attribute__((ext_vector_type(4))) float;

static __device__ __forceinline__ short f2bf(float f) {
    __hip_bfloat16 h = __float2bfloat16(f);   // RNE
    union { __hip_bfloat16 h; short s; } u; u.h = h;
    return u.s;
}
static __device__ __forceinline__ float bf2f(short s) {
    union { unsigned u; float f; } v;
    v.u = ((unsigned)(unsigned short)s) << 16;
    return v.f;
}

// ---------------- conv (unchanged) ----------------
template<int CIN, int S, int CO_T, int TT>
__global__ __launch_bounds__(256) void conv_wave_kernel(
    const float* __restrict__ x, const float* __restrict__ w,
    const float* __restrict__ bias, float* __restrict__ y,
    int B, int Lin, int Lout, int Cout)
{
    constexpr int NT   = 64 * TT;
    constexpr int XLEN = (NT - 1) * S + 7;
    __shared__ float xs[CIN][XLEN];

    int tb  = blockIdx.x;
    int cbk = blockIdx.y;
    int b   = blockIdx.z;
    int t0  = tb * NT;
    int tid  = threadIdx.x;
    int lane = tid & 63;
    int wv   = __builtin_amdgcn_readfirstlane(tid >> 6);

    const float* xb = x + (size_t)b * CIN * Lin;
    int g0 = t0 * S - 6;
    for (int i = tid; i < CIN * XLEN; i += 256) {
        int ci = i / XLEN, xo = i % XLEN;
        int gx = g0 + xo;
        xs[ci][xo] = (gx >= 0 && gx < Lin) ? xb[(size_t)ci * Lin + gx] : 0.0f;
    }
    __syncthreads();

    int co0 = cbk * (4 * CO_T) + wv * CO_T;
    const float* wbase = w + (size_t)co0 * CIN * 7;

    float acc[CO_T][TT];
    #pragma unroll
    for (int c = 0; c < CO_T; ++c)
        #pragma unroll
        for (int u = 0; u < TT; ++u) acc[c][u] = 0.0f;

    for (int ci = 0; ci < CIN; ++ci) {
        float xw[TT][7];
        #pragma unroll
        for (int u = 0; u < TT; ++u)
            #pragma unroll
            for (int k = 0; k < 7; ++k)
                xw[u][k] = xs[ci][(lane + 64 * u) * S + k];
        #pragma unroll
        for (int c = 0; c < CO_T; ++c) {
            const float* wp = wbase + (size_t)c * CIN * 7 + ci * 7;
            #pragma unroll
            for (int k = 0; k < 7; ++k) {
                float wk = wp[k];
                #pragma unroll
                for (int u = 0; u < TT; ++u)
                    acc[c][u] = fmaf(wk, xw[u][k], acc[c][u]);
            }
        }
    }

    #pragma unroll
    for (int u = 0; u < TT; ++u) {
        int t = t0 + lane + 64 * u;
        if (t < Lout) {
            #pragma unroll
            for (int c = 0; c < CO_T; ++c) {
                float v = acc[c][u] + bias[co0 + c];
                y[((size_t)b * Cout + co0 + c) * Lout + t] = v > 0.0f ? v : expm1f(v);
            }
        }
    }
}

// ---------------- VQ prep: cc (fp32) + codebook hi/lo bf16 B-fragments ------
// layout: [cb][nt(64)][kc(2)][hl(2)][lane(64)][j(8)] bf16; for mfma_16x16x32:
// B element (k = kc*32 + (lane>>4)*8 + j, n = nt*16 + (lane&15))
__global__ __launch_bounds__(256) void vq_prep_kernel(
    const float* __restrict__ cbs, float* __restrict__ cc, short* __restrict__ cbf)
{
    int c = blockIdx.x * 256 + threadIdx.x;   // 0..2047
    if (c >= 2048) return;
    int cb = c >> 10, nl = c & 1023;
    const float* row = cbs + (size_t)c * 64;
    float v[64];
    float s = 0.f;
    #pragma unroll
    for (int i = 0; i < 16; ++i) {
        float4 q = ((const float4*)row)[i];
        v[4*i+0] = q.x; v[4*i+1] = q.y; v[4*i+2] = q.z; v[4*i+3] = q.w;
        s += q.x*q.x + q.y*q.y + q.z*q.z + q.w*q.w;
    }
    cc[c] = s;
    int nt = nl >> 4, nc = nl & 15;
    #pragma unroll
    for (int kc = 0; kc < 2; ++kc)
        #pragma unroll
        for (int lh = 0; lh < 4; ++lh) {
            bf16x8 ph, pl;
            #pragma unroll
            for (int j = 0; j < 8; ++j) {
                float f = v[kc*32 + lh*8 + j];
                short h = f2bf(f);
                ph[j] = h;
                pl[j] = f2bf(f - bf2f(h));
            }
            size_t base = ((((size_t)cb*64 + nt)*2 + kc)*2);
            *(bf16x8*)(cbf + ((base + 0)*64 + (lh*16 + nc)) * 8) = ph;
            *(bf16x8*)(cbf + ((base + 1)*64 + (lh*16 + nc)) * 8) = pl;
        }
}

__global__ void zero_cnt_kernel(int* cnt) {
    if (threadIdx.x == 0 && blockIdx.x == 0) *cnt = 0;
}

// ---------------- VQ main: split-bf16 MFMA + best/second + flag -------------
#define VQ_MARGIN 0.02f

__global__ __launch_bounds__(256) void vq_mfma_kernel(
    const float* __restrict__ z, const short* __restrict__ cbf,
    const float* __restrict__ ccg, int* __restrict__ out,
    int* __restrict__ cnt, int* __restrict__ list)
{
    __shared__ short zf[2][8*2*64*8];     // 32 KB: A-frags [hl][mt(8)][kc(2)][lane][j]
    __shared__ short cbc[8*2*2*64*8];     // 32 KB: B-frag chunk (128 codes, hi+lo)
    __shared__ float ccl[128];

    const int T = 2000;
    int mblk = blockIdx.x;   // 16 m-blocks of 128 t
    int cb   = blockIdx.y;
    int b    = blockIdx.z;
    int t0   = mblk * 128;
    int tid  = threadIdx.x;
    int lane = tid & 63;
    int wv   = tid >> 6;

    // ---- stage z tile (128 t x 64 d) into hi/lo bf16 A-fragments ----
    const float* zb = z + ((size_t)b*128 + (size_t)cb*64) * T;
    bool tail = (t0 + 128 > T);
    #pragma unroll
    for (int p = 0; p < 8; ++p) {
        int d    = p*8 + (tid >> 5);
        int toff = (tid & 31) * 4;
        float qa[4];
        if (!tail) {
            float4 q = *(const float4*)(zb + (size_t)d*T + t0 + toff);
            qa[0]=q.x; qa[1]=q.y; qa[2]=q.z; qa[3]=q.w;
        } else {
            #pragma unroll
            for (int u = 0; u < 4; ++u) {
                int tt = t0 + toff + u; if (tt > T-1) tt = T-1;
                qa[u] = zb[(size_t)d*T + tt];
            }
        }
        #pragma unroll
        for (int u = 0; u < 4; ++u) {
            int tl = toff + u;
            int mt = tl >> 4;
            int lw = ((d & 31) >> 3) * 16 + (tl & 15);
            int kc = d >> 5;
            int idx = (((mt*2 + kc)*64) + lw)*8 + (d & 7);
            short h = f2bf(qa[u]);
            zf[0][idx] = h;
            zf[1][idx] = f2bf(qa[u] - bf2f(h));
        }
    }
    __syncthreads();

    // A-fragments for this wave (rows t0 + (wv*2+mtl)*16 + ...)
    bf16x8 ah[2][2], al[2][2];
    #pragma unroll
    for (int mtl = 0; mtl < 2; ++mtl)
        #pragma unroll
        for (int kc = 0; kc < 2; ++kc) {
            int idx = ((((wv*2+mtl)*2 + kc)*64) + lane)*8;
            ah[mtl][kc] = *(const bf16x8*)&zf[0][idx];
            al[mtl][kc] = *(const bf16x8*)&zf[1][idx];
        }

    float best[2][4], second[2][4]; int bidx[2][4];
    #pragma unroll
    for (int m = 0; m < 2; ++m)
        #pragma unroll
        for (int j = 0; j < 4; ++j) { best[m][j] = 3.4e38f; second[m][j] = 3.4e38f; bidx[m][j] = 0; }

    const short* cbase = cbf + (size_t)cb * (64*2*2*64*8);
    const float* ccb   = ccg + cb * 1024;

    for (int ch = 0; ch < 8; ++ch) {   // 8 chunks of 128 codes
        __syncthreads();   // previous chunk consumed
        {
            const float4* src = (const float4*)(cbase + (size_t)ch * (8*2*2*64*8));
            float4* dst = (float4*)cbc;
            #pragma unroll
            for (int i = 0; i < 8; ++i) dst[tid + 256*i] = src[tid + 256*i];
            if (tid < 128) ccl[tid] = ccb[ch*128 + tid];
        }
        __syncthreads();

        for (int ntl = 0; ntl < 8; ++ntl) {
            bf16x8 b0h = *(const bf16x8*)&cbc[(((ntl*2 + 0)*2 + 0)*64 + lane)*8];
            bf16x8 b0l = *(const bf16x8*)&cbc[(((ntl*2 + 0)*2 + 1)*64 + lane)*8];
            bf16x8 b1h = *(const bf16x8*)&cbc[(((ntl*2 + 1)*2 + 0)*64 + lane)*8];
            bf16x8 b1l = *(const bf16x8*)&cbc[(((ntl*2 + 1)*2 + 1)*64 + lane)*8];
            float ccv = ccl[ntl*16 + (lane & 15)];
            int  code = ch*128 + ntl*16 + (lane & 15);
            #pragma unroll
            for (int mtl = 0; mtl < 2; ++mtl) {
                // two independent 3-chains covering zh.ch(kc0,kc1), zh.cl(kc0,kc1), zl.ch(kc0,kc1)
                f32x4 p = {0.f,0.f,0.f,0.f}, q = {0.f,0.f,0.f,0.f};
                p = __builtin_amdgcn_mfma_f32_16x16x32_bf16(ah[mtl][0], b0h, p, 0, 0, 0);
                q = __builtin_amdgcn_mfma_f32_16x16x32_bf16(ah[mtl][1], b1h, q, 0, 0, 0);
                p = __builtin_amdgcn_mfma_f32_16x16x32_bf16(ah[mtl][0], b0l, p, 0, 0, 0);
                q = __builtin_amdgcn_mfma_f32_16x16x32_bf16(ah[mtl][1], b1l, q, 0, 0, 0);
                p = __builtin_amdgcn_mfma_f32_16x16x32_bf16(al[mtl][0], b0h, p, 0, 0, 0);
                q = __builtin_amdgcn_mfma_f32_16x16x32_bf16(al[mtl][1], b1h, q, 0, 0, 0);
                #pragma unroll
                for (int j = 0; j < 4; ++j) {
                    float s = fmaf(-2.0f, p[j] + q[j], ccv);
                    bool lt = s < best[mtl][j];
                    second[mtl][j] = fminf(second[mtl][j], fmaxf(best[mtl][j], s));
                    best[mtl][j]   = fminf(best[mtl][j], s);
                    bidx[mtl][j]   = lt ? code : bidx[mtl][j];
                }
            }
        }
    }

    // merge across the 16 col-lanes (same rows, different code slices)
    #pragma unroll
    for (int m = 0; m < 2; ++m)
        #pragma unroll
        for (int j = 0; j < 4; ++j) {
            float bv = best[m][j], sv = second[m][j]; int bi = bidx[m][j];
            #pragma unroll
            for (int d = 1; d < 16; d <<= 1) {
                float ob = __shfl_xor(bv, d, 64);
                float os = __shfl_xor(sv, d, 64);
                int   oi = __shfl_xor(bi, d, 64);
                float loser = fmaxf(bv, ob);
                sv = fminf(fminf(sv, os), loser);
                bool sw = ob < bv;
                bv = fminf(bv, ob);
                bi = sw ? oi : bi;
            }
            if ((lane & 15) == 0) {
                int t = t0 + (wv*2 + m)*16 + (lane >> 4)*4 + j;
                if (t < T) {
                    out[((size_t)cb*64 + b)*T + t] = bi;
                    if (sv - bv < VQ_MARGIN) {
                        int pos = atomicAdd(cnt, 1);
                        list[pos] = (cb << 17) | (b << 11) | t;
                    }
                }
            }
        }
}

// ---------------- VQ rescore: exact fp32 for flagged t ----------------------
__global__ __launch_bounds__(256) void vq_rescore_kernel(
    const float* __restrict__ z, const float* __restrict__ cbs,
    const float* __restrict__ ccg, const int* __restrict__ cnt,
    const int* __restrict__ list, int* __restrict__ out)
{
    const int T = 2000;
    int lane = threadIdx.x & 63;
    int gw = (blockIdx.x * 256 + threadIdx.x) >> 6;   // global wave id
    int count = *cnt;

    for (int i = gw; i < count; i += 1024) {
        int e = list[i];
        int cb = e >> 17, b = (e >> 11) & 63, t = e & 2047;
        const float* zb = z + ((size_t)b*128 + (size_t)cb*64) * T + t;
        float zr[64];
        #pragma unroll
        for (int d = 0; d < 64; ++d) zr[d] = zb[(size_t)d * T];

        const float* cbase = cbs + (size_t)cb * 1024 * 64;
        const float* ccb   = ccg + cb * 1024;
        float bv = 3.4e38f; int bi = 0x7fffffff;
        for (int ii = 0; ii < 16; ++ii) {
            int code = ii*64 + lane;
            const float4* cp = (const float4*)(cbase + (size_t)code * 64);
            float d0 = 0.f, d1 = 0.f, d2 = 0.f, d3 = 0.f;
            #pragma unroll
            for (int q = 0; q < 16; ++q) {
                float4 cv = cp[q];
                d0 = fmaf(zr[4*q+0], cv.x, d0);
                d1 = fmaf(zr[4*q+1], cv.y, d1);
                d2 = fmaf(zr[4*q+2], cv.z, d2);
                d3 = fmaf(zr[4*q+3], cv.w, d3);
            }
            float s = fmaf(-2.0f, (d0 + d1) + (d2 + d3), ccb[code]);
            if (s < bv) { bv = s; bi = code; }
        }
        #pragma unroll
        for (int d = 1; d < 64; d <<= 1) {
            float ov = __shfl_xor(bv, d, 64);
            int   oi = __shfl_xor(bi, d, 64);
            if (ov < bv || (ov == bv && oi < bi)) { bv = ov; bi = oi; }
        }
        if (lane == 0) out[((size_t)cb*64 + b)*T + t] = bi;
    }
}

extern "C" void kernel_launch(void* const* d_in, const int* in_sizes, int n_in,
                              void* d_out, int out_size, void* d_ws, size_t ws_size,
                              hipStream_t stream)
{
    const float* x   = (const float*)d_in[0];
    const float* w0  = (const float*)d_in[1];
    const float* b0  = (const float*)d_in[2];
    const float* w1  = (const float*)d_in[3];
    const float* b1  = (const float*)d_in[4];
    const float* w2  = (const float*)d_in[5];
    const float* b2  = (const float*)d_in[6];
    const float* w3  = (const float*)d_in[7];
    const float* b3  = (const float*)d_in[8];
    const float* wq  = (const float*)d_in[9];
    const float* bq  = (const float*)d_in[10];
    const float* cbs = (const float*)d_in[11];
    int* out = (int*)d_out;

    constexpr int B = 64;
    constexpr size_t BUF = 24576000;
    float* bufA = (float*)d_ws;
    float* bufB = bufA + BUF;
    // prep area: inside bufB beyond conv3/conv4's 8.192M floats (at +16M floats).
    float* prep = bufB + 16000000;
    short* cbf  = (short*)prep;                 // 262144 bf16 (hi+lo frags)
    float* cc   = prep + 131072;                // 2048 f32
    int*   cnt  = (int*)(cc + 2048);            // 1 int (+pad)
    int*   list = cnt + 4;                      // flagged-t list

    // conv0: (B,1,48000) -> (B,16,24000)
    conv_wave_kernel<1, 2, 4, 2><<<dim3(188, 1, B), 256, 0, stream>>>(
        x, w0, b0, bufA, B, 48000, 24000, 16);
    // conv1: (B,16,24000) -> (B,32,12000)
    conv_wave_kernel<16, 2, 8, 2><<<dim3(94, 1, B), 256, 0, stream>>>(
        bufA, w1, b1, bufB, B, 24000, 12000, 32);
    // conv2: (B,32,12000) -> (B,64,6000)
    conv_wave_kernel<32, 2, 8, 2><<<dim3(47, 2, B), 256, 0, stream>>>(
        bufB, w2, b2, bufA, B, 12000, 6000, 64);

    // prep (bufB prep region free after conv2)
    vq_prep_kernel<<<8, 256, 0, stream>>>(cbs, cc, cbf);
    zero_cnt_kernel<<<1, 64, 0, stream>>>(cnt);

    // conv3: (B,64,6000) -> (B,64,2000)
    conv_wave_kernel<64, 3, 8, 1><<<dim3(32, 2, B), 256, 0, stream>>>(
        bufA, w3, b3, bufB, B, 6000, 2000, 64);
    // conv4: (B,64,2000) -> (B,128,2000)
    conv_wave_kernel<64, 1, 8, 2><<<dim3(16, 4, B), 256, 0, stream>>>(
        bufB, wq, bq, bufA, B, 2000, 2000, 128);

    // VQ: split-bf16 MFMA + flag, then exact fp32 rescore of flagged t
    vq_mfma_kernel<<<dim3(16, 2, B), 256, 0, stream>>>(bufA, cbf, cc, out, cnt, list);
    vq_rescore_kernel<<<256, 256, 0, stream>>>(bufA, cbs, cc, cnt, list, out);
}